// Round 2
// baseline (1845.147 us; speedup 1.0000x reference)
//
#include <hip/hip_runtime.h>
#include <math.h>

#define FDIM 32
#define NBASIS 8

constexpr float RCUT_C = 20.0f;
constexpr float PI_F = 3.14159265358979323846f;
constexpr float EV2KJ_C = 96.4853f;
constexpr float NM2A_C = 10.0f;

__device__ __forceinline__ float sigmoidf_(float z) { return 1.0f / (1.0f + __expf(-z)); }

// ---------------- CSR build: histogram, scan, scatter ----------------
__global__ __launch_bounds__(256) void hist_dst(
    const int* __restrict__ eidx, int* __restrict__ counts, int E)
{
    for (int e = blockIdx.x * 256 + threadIdx.x; e < E; e += gridDim.x * 256)
        atomicAdd(&counts[eidx[E + e]], 1);
}

__global__ __launch_bounds__(1024) void scan_counts(
    const int* __restrict__ counts, int* __restrict__ rowptr,
    int* __restrict__ cursor, int N)
{
    __shared__ int lds[1024];
    const int t = threadIdx.x;
    const int chunk = (N + 1023) / 1024;
    const int start = t * chunk;
    const int end = min(start + chunk, N);
    int local = 0;
    for (int i = start; i < end; i++) local += counts[i];
    lds[t] = local;
    __syncthreads();
    for (int off = 1; off < 1024; off <<= 1) {
        int v = (t >= off) ? lds[t - off] : 0;
        __syncthreads();
        lds[t] += v;
        __syncthreads();
    }
    int run = lds[t] - local;  // exclusive prefix
    for (int i = start; i < end; i++) {
        rowptr[i] = run;
        cursor[i] = run;
        run += counts[i];
    }
    if (t == 1023) rowptr[N] = lds[1023];
}

__global__ __launch_bounds__(256) void scatter_edges(
    const int* __restrict__ eidx, int* __restrict__ cursor,
    int* __restrict__ order, int E)
{
    for (int e = blockIdx.x * 256 + threadIdx.x; e < E; e += gridDim.x * 256) {
        int p = atomicAdd(&cursor[eidx[E + e]], 1);
        order[p] = e;
    }
}

// ---------------- edge forward (gather by dst): s (N*32), v (N*3*32) ----------------
__global__ __launch_bounds__(256) void edge_fwd_gather(
    const float* __restrict__ pos, const int* __restrict__ types,
    const int* __restrict__ eidx,
    const int* __restrict__ rowptr, const int* __restrict__ order,
    const float* __restrict__ Wr1, const float* __restrict__ br1,
    const float* __restrict__ Wr2, const float* __restrict__ temb,
    float* __restrict__ s_acc, float* __restrict__ v_acc, int N, int E)
{
    __shared__ float sW1[NBASIS * FDIM], sb1[FDIM], sTE[96];
    __shared__ float sW2p[2048];  // pair-interleaved: [f][lane] -> (W2[f][lane], W2[f][lane+32])
    for (int i = threadIdx.x; i < NBASIS * FDIM; i += 256) sW1[i] = Wr1[i];
    for (int i = threadIdx.x; i < FDIM; i += 256) sb1[i] = br1[i];
    for (int i = threadIdx.x; i < 1024; i += 256) {
        int f = i >> 5, l = i & 31;
        sW2p[(f * 32 + l) * 2 + 0] = Wr2[f * 64 + l];
        sW2p[(f * 32 + l) * 2 + 1] = Wr2[f * 64 + 32 + l];
    }
    for (int i = threadIdx.x; i < 96; i += 256) sTE[i] = temb[i];
    __syncthreads();
    const float2* sW2p2 = (const float2*)sW2p;

    const int lane = threadIdx.x & 31;
    const int a = blockIdx.x * 8 + (threadIdx.x >> 5);
    if (a >= N) return;

    const float ax = pos[a * 3 + 0] * NM2A_C;
    const float ay = pos[a * 3 + 1] * NM2A_C;
    const float az = pos[a * 3 + 2] * NM2A_C;
    const int row0 = rowptr[a], row1 = rowptr[a + 1];

    float s_sum = 0.0f, vx = 0.0f, vy = 0.0f, vz = 0.0f;

    for (int j0 = row0; j0 < row1; j0 += 32) {
        const int m = min(32, row1 - j0);
        int srcl = 0, ty = 0;
        float px = 0, py = 0, pz = 0;
        if (lane < m) {
            int e = order[j0 + lane];
            srcl = eidx[e];
            px = pos[srcl * 3 + 0] * NM2A_C;
            py = pos[srcl * 3 + 1] * NM2A_C;
            pz = pos[srcl * 3 + 2] * NM2A_C;
            ty = types[srcl];
        }
        for (int i = 0; i < m; i++) {
            float rx = ax - __shfl(px, i, 32);
            float ry = ay - __shfl(py, i, 32);
            float rz = az - __shfl(pz, i, 32);
            int tyi = __shfl(ty, i, 32);
            float r2 = rx * rx + ry * ry + rz * rz + 1e-12f;
            float r = sqrtf(r2);
            float rinv = 1.0f / r;
            float x = r * (1.0f / RCUT_C);
            float x2 = x * x, x4 = x2 * x2, x6 = x4 * x2, x7 = x6 * x, x8 = x6 * x2;
            float env = (x < 1.0f) ? (1.0f - 28.0f * x6 + 48.0f * x7 - 21.0f * x8) : 0.0f;

            float th = PI_F * x, s1, c1;
            __sincosf(th, &s1, &c1);
            float sp = 0.0f, sn = s1;
            float z = sb1[lane];
            #pragma unroll
            for (int n = 0; n < NBASIS; n++) {
                z += (sn * rinv) * sW1[n * FDIM + lane];
                float snx = 2.0f * c1 * sn - sp; sp = sn; sn = snx;
            }
            float sg = sigmoidf_(z);
            float q = z * sg;

            float rw0 = 0.0f, rw1 = 0.0f;
            #pragma unroll
            for (int f = 0; f < FDIM; f++) {
                float qv = __shfl(q, f, 32);
                float2 w = sW2p2[f * 32 + lane];
                rw0 += qv * w.x;
                rw1 += qv * w.y;
            }
            float hs = sTE[tyi * FDIM + lane];
            s_sum += hs * rw0 * env;
            float hw1 = hs * rw1 * env;
            vx += hw1 * rx * rinv;
            vy += hw1 * ry * rinv;
            vz += hw1 * rz * rinv;
        }
    }
    s_acc[(size_t)a * FDIM + lane] = s_sum;
    v_acc[(size_t)a * 96 + 0 * 32 + lane] = vx;
    v_acc[(size_t)a * 96 + 1 * 32 + lane] = vy;
    v_acc[(size_t)a * 96 + 2 * 32 + lane] = vz;
}

// -------- atom MLP: energy partials + g_s/g_v (in-place over s/v) --------
__global__ __launch_bounds__(256) void atom_mlp(
    const int* __restrict__ types, const float* __restrict__ temb,
    const float* __restrict__ Wself, const float* __restrict__ Wo1,
    const float* __restrict__ bo1, const float* __restrict__ Wo2,
    float* __restrict__ s_acc, float* __restrict__ v_acc,
    float* __restrict__ e_partial, int N)
{
    __shared__ float sWs[FDIM * FDIM], sWsT[FDIM * FDIM];
    __shared__ float sWo1[2 * FDIM * FDIM], sWo1T[2 * FDIM * FDIM];
    __shared__ float sb[FDIM], sW2o[FDIM], sTE[96];
    __shared__ float gred[8];
    for (int i = threadIdx.x; i < FDIM * FDIM; i += 256) {
        sWs[i] = Wself[i];
        sWsT[i] = Wself[(i & 31) * FDIM + (i >> 5)];
    }
    for (int i = threadIdx.x; i < 2 * FDIM * FDIM; i += 256) {
        sWo1[i] = Wo1[i];
        sWo1T[i] = Wo1[(i & 63) * FDIM + (i >> 6)];
    }
    for (int i = threadIdx.x; i < FDIM; i += 256) { sb[i] = bo1[i]; sW2o[i] = Wo2[i]; }
    for (int i = threadIdx.x; i < 96; i += 256) sTE[i] = temb[i];
    __syncthreads();

    const int lane = threadIdx.x & 31;
    const int g = threadIdx.x >> 5;
    int a = blockIdx.x * 8 + g;
    const bool valid = (a < N);
    if (!valid) a = 0;

    float sv = s_acc[(size_t)a * FDIM + lane];
    float vx = v_acc[(size_t)a * 96 + 0 * 32 + lane];
    float vy = v_acc[(size_t)a * 96 + 1 * 32 + lane];
    float vz = v_acc[(size_t)a * 96 + 2 * 32 + lane];
    float h = sTE[types[a] * FDIM + lane];
    float vn = sqrtf(vx * vx + vy * vy + vz * vz + 1e-12f);

    float row = h;
    #pragma unroll
    for (int f = 0; f < FDIM; f++) {
        float t = __shfl(sv, f, 32);
        row += t * sWs[f * FDIM + lane];
    }
    float u = sb[lane];
    #pragma unroll
    for (int j = 0; j < FDIM; j++) {
        float rv = __shfl(row, j, 32);
        float vv = __shfl(vn, j, 32);
        u += rv * sWo1[j * FDIM + lane] + vv * sWo1[(j + FDIM) * FDIM + lane];
    }
    float sg = sigmoidf_(u);
    float au = u * sg;
    float pa = valid ? au * sW2o[lane] : 0.0f;
    #pragma unroll
    for (int m = 16; m; m >>= 1) pa += __shfl_xor(pa, m, 32);
    if (lane == 0) gred[g] = pa;

    float gu = sW2o[lane] * (sg * (1.0f + u * (1.0f - sg)));
    float gfr = 0.0f, gfv = 0.0f;
    #pragma unroll
    for (int k = 0; k < FDIM; k++) {
        float gv_ = __shfl(gu, k, 32);
        gfr += gv_ * sWo1T[k * 64 + lane];
        gfv += gv_ * sWo1T[k * 64 + 32 + lane];
    }
    float gs = 0.0f;
    #pragma unroll
    for (int k = 0; k < FDIM; k++) {
        float gr = __shfl(gfr, k, 32);
        gs += gr * sWsT[k * FDIM + lane];
    }
    __syncthreads();
    if (valid) {
        s_acc[(size_t)a * FDIM + lane] = gs;
        float sc = gfv / vn;
        v_acc[(size_t)a * 96 + 0 * 32 + lane] = sc * vx;
        v_acc[(size_t)a * 96 + 1 * 32 + lane] = sc * vy;
        v_acc[(size_t)a * 96 + 2 * 32 + lane] = sc * vz;
    }
    if (threadIdx.x == 0) {
        float t = 0.0f;
        #pragma unroll
        for (int i = 0; i < 8; i++) t += gred[i];
        e_partial[blockIdx.x] = t;
    }
}

// ---------------- edge backward (gather by dst): forces ----------------
__global__ __launch_bounds__(256) void edge_bwd_gather(
    const float* __restrict__ pos, const int* __restrict__ types,
    const int* __restrict__ eidx,
    const int* __restrict__ rowptr, const int* __restrict__ order,
    const float* __restrict__ Wr1, const float* __restrict__ br1,
    const float* __restrict__ Wr2, const float* __restrict__ temb,
    const float* __restrict__ g_s, const float* __restrict__ g_v,
    float* __restrict__ forces, int N, int E)
{
    __shared__ float sW1[NBASIS * FDIM], sb1[FDIM], sTE[96];
    __shared__ float sW2p[2048];       // [f][lane] pairs (fwd orientation)
    __shared__ float sW2Tp[32 * 33 * 2]; // [j][f] pairs, padded: (W2[f][j], W2[f][j+32])
    for (int i = threadIdx.x; i < NBASIS * FDIM; i += 256) sW1[i] = Wr1[i];
    for (int i = threadIdx.x; i < FDIM; i += 256) sb1[i] = br1[i];
    for (int i = threadIdx.x; i < 1024; i += 256) {
        int f = i >> 5, l = i & 31;
        float w0 = Wr2[f * 64 + l], w1 = Wr2[f * 64 + 32 + l];
        sW2p[(f * 32 + l) * 2 + 0] = w0;
        sW2p[(f * 32 + l) * 2 + 1] = w1;
        sW2Tp[(l * 33 + f) * 2 + 0] = w0;   // here l plays role of j, f of lane
        sW2Tp[(l * 33 + f) * 2 + 1] = w1;
    }
    for (int i = threadIdx.x; i < 96; i += 256) sTE[i] = temb[i];
    __syncthreads();
    const float2* sW2p2 = (const float2*)sW2p;
    const float2* sW2Tp2 = (const float2*)sW2Tp;

    const int lane = threadIdx.x & 31;
    const int a = blockIdx.x * 8 + (threadIdx.x >> 5);
    if (a >= N) return;

    const float ax = pos[a * 3 + 0] * NM2A_C;
    const float ay = pos[a * 3 + 1] * NM2A_C;
    const float az = pos[a * 3 + 2] * NM2A_C;
    const float gm0  = g_s[(size_t)a * FDIM + lane];
    const float gm1x = g_v[(size_t)a * 96 + 0 * 32 + lane];
    const float gm1y = g_v[(size_t)a * 96 + 1 * 32 + lane];
    const float gm1z = g_v[(size_t)a * 96 + 2 * 32 + lane];
    const int row0 = rowptr[a], row1 = rowptr[a + 1];
    const float SC = EV2KJ_C * NM2A_C;

    float fdx = 0.0f, fdy = 0.0f, fdz = 0.0f;

    for (int j0 = row0; j0 < row1; j0 += 32) {
        const int m = min(32, row1 - j0);
        int srcl = 0, ty = 0;
        float px = 0, py = 0, pz = 0;
        if (lane < m) {
            int e = order[j0 + lane];
            srcl = eidx[e];
            px = pos[srcl * 3 + 0] * NM2A_C;
            py = pos[srcl * 3 + 1] * NM2A_C;
            pz = pos[srcl * 3 + 2] * NM2A_C;
            ty = types[srcl];
        }
        for (int i = 0; i < m; i++) {
            float rx = ax - __shfl(px, i, 32);
            float ry = ay - __shfl(py, i, 32);
            float rz = az - __shfl(pz, i, 32);
            int tyi = __shfl(ty, i, 32);
            int srci = __shfl(srcl, i, 32);
            float r2 = rx * rx + ry * ry + rz * rz + 1e-12f;
            float r = sqrtf(r2);
            float rinv = 1.0f / r;
            float x = r * (1.0f / RCUT_C);
            float x2 = x * x, x4 = x2 * x2, x5 = x4 * x, x6 = x4 * x2, x7 = x6 * x, x8 = x6 * x2;
            float env = (x < 1.0f) ? (1.0f - 28.0f * x6 + 48.0f * x7 - 21.0f * x8) : 0.0f;
            float denv = (x < 1.0f) ? (-168.0f * x5 + 336.0f * x6 - 168.0f * x7) * (1.0f / RCUT_C) : 0.0f;

            float th = PI_F * x, s1, c1;
            __sincosf(th, &s1, &c1);
            float sp = 0.0f, sn = s1, cp = 1.0f, cn = c1;
            float z = sb1[lane];
            float tacc = 0.0f;
            #pragma unroll
            for (int n = 0; n < NBASIS; n++) {
                float basis = sn * rinv;
                float wv = sW1[n * FDIM + lane];
                z += basis * wv;
                float dbdr = (PI_F * (float)(n + 1) * (1.0f / RCUT_C)) * cn * rinv - basis * rinv;
                tacc += dbdr * wv;
                float snx = 2.0f * c1 * sn - sp; sp = sn; sn = snx;
                float cnx = 2.0f * c1 * cn - cp; cp = cn; cn = cnx;
            }
            float sg = sigmoidf_(z);
            float q = z * sg;

            float rw0 = 0.0f, rw1 = 0.0f;
            #pragma unroll
            for (int f = 0; f < FDIM; f++) {
                float qv = __shfl(q, f, 32);
                float2 w = sW2p2[f * 32 + lane];
                rw0 += qv * w.x;
                rw1 += qv * w.y;
            }
            float hs = sTE[tyi * FDIM + lane];
            float rhx = rx * rinv, rhy = ry * rinv, rhz = rz * rinv;
            float gw0 = hs * gm0;
            float gw1 = hs * (gm1x * rhx + gm1y * rhy + gm1z * rhz);
            float hw1 = hs * rw1 * env;
            float grx = hw1 * gm1x, gry = hw1 * gm1y, grz = hw1 * gm1z;
            float genv = gw0 * rw0 + gw1 * rw1;
            float gr0 = gw0 * env, gr1 = gw1 * env;

            float gq = 0.0f;
            #pragma unroll
            for (int j = 0; j < FDIM; j++) {
                float a0 = __shfl(gr0, j, 32);
                float a1 = __shfl(gr1, j, 32);
                float2 wt = sW2Tp2[j * 33 + lane];
                gq += a0 * wt.x + a1 * wt.y;
            }
            float gz = gq * (sg * (1.0f + z * (1.0f - sg)));
            float gcomb = gz * tacc + genv * denv;   // combined g_r partial per lane

            #pragma unroll
            for (int mm = 16; mm; mm >>= 1) {
                grx += __shfl_xor(grx, mm, 32);
                gry += __shfl_xor(gry, mm, 32);
                grz += __shfl_xor(grz, mm, 32);
                gcomb += __shfl_xor(gcomb, mm, 32);
            }

            float dotg = grx * rhx + gry * rhy + grz * rhz;
            float gex = gcomb * rhx + (grx - dotg * rhx) * rinv;
            float gey = gcomb * rhy + (gry - dotg * rhy) * rinv;
            float gez = gcomb * rhz + (grz - dotg * rhz) * rinv;

            fdx += gex; fdy += gey; fdz += gez;
            if (lane < 3) {
                float comp = (lane == 0) ? gex : ((lane == 1) ? gey : gez);
                unsafeAtomicAdd(&forces[(size_t)srci * 3 + lane], SC * comp);
            }
        }
    }
    if (lane < 3) {
        float comp = (lane == 0) ? fdx : ((lane == 1) ? fdy : fdz);
        unsafeAtomicAdd(&forces[(size_t)a * 3 + lane], -SC * comp);
    }
}

// ---------------- reductions & correction ----------------
__global__ __launch_bounds__(256) void reduce_energy(
    const float* __restrict__ e_partial, int n, float* __restrict__ out)
{
    __shared__ float red[256];
    float s = 0.0f;
    for (int i = threadIdx.x; i < n; i += 256) s += e_partial[i];
    red[threadIdx.x] = s;
    __syncthreads();
    for (int k = 128; k; k >>= 1) {
        if (threadIdx.x < k) red[threadIdx.x] += red[threadIdx.x + k];
        __syncthreads();
    }
    if (threadIdx.x == 0) out[0] = red[0] * EV2KJ_C;
}

__global__ __launch_bounds__(256) void reduce_net(
    const float* __restrict__ f, const float* __restrict__ masses,
    float* __restrict__ accum, int N)
{
    float nx = 0, ny = 0, nz = 0, ms = 0;
    for (int i = blockIdx.x * 256 + threadIdx.x; i < N; i += gridDim.x * 256) {
        nx += f[i * 3 + 0]; ny += f[i * 3 + 1]; nz += f[i * 3 + 2]; ms += masses[i];
    }
    #pragma unroll
    for (int m = 32; m; m >>= 1) {
        nx += __shfl_xor(nx, m, 64);
        ny += __shfl_xor(ny, m, 64);
        nz += __shfl_xor(nz, m, 64);
        ms += __shfl_xor(ms, m, 64);
    }
    __shared__ float red[4][4];
    int w = threadIdx.x >> 6;
    if ((threadIdx.x & 63) == 0) { red[w][0] = nx; red[w][1] = ny; red[w][2] = nz; red[w][3] = ms; }
    __syncthreads();
    if (threadIdx.x == 0) {
        float a0 = 0, a1 = 0, a2 = 0, a3 = 0;
        for (int i = 0; i < 4; i++) { a0 += red[i][0]; a1 += red[i][1]; a2 += red[i][2]; a3 += red[i][3]; }
        unsafeAtomicAdd(accum + 0, a0);
        unsafeAtomicAdd(accum + 1, a1);
        unsafeAtomicAdd(accum + 2, a2);
        unsafeAtomicAdd(accum + 3, a3);
    }
}

__global__ __launch_bounds__(256) void correct_forces(
    float* __restrict__ f, const float* __restrict__ masses,
    const float* __restrict__ accum, int N)
{
    int i = blockIdx.x * 256 + threadIdx.x;
    if (i < N) {
        float c = masses[i] / accum[3];
        f[i * 3 + 0] -= c * accum[0];
        f[i * 3 + 1] -= c * accum[1];
        f[i * 3 + 2] -= c * accum[2];
    }
}

extern "C" void kernel_launch(void* const* d_in, const int* in_sizes, int n_in,
                              void* d_out, int out_size, void* d_ws, size_t ws_size,
                              hipStream_t stream)
{
    (void)n_in; (void)ws_size;
    const float* pos    = (const float*)d_in[0];
    const float* masses = (const float*)d_in[1];
    const float* temb   = (const float*)d_in[2];
    const float* Wr1    = (const float*)d_in[3];
    const float* br1    = (const float*)d_in[4];
    const float* Wr2    = (const float*)d_in[5];
    const float* Wself  = (const float*)d_in[6];
    const float* Wo1    = (const float*)d_in[7];
    const float* bo1    = (const float*)d_in[8];
    const float* Wo2    = (const float*)d_in[9];
    const int* types    = (const int*)d_in[10];
    const int* eidx     = (const int*)d_in[11];
    const int N = in_sizes[1];
    const int E = in_sizes[11] / 2;

    float* out = (float*)d_out;
    float* forces = out + 1;

    float* ws = (float*)d_ws;
    float* s_acc = ws;                               // N*32
    float* v_acc = s_acc + (size_t)N * FDIM;         // N*96
    int nAtomBlocks = (N + 7) / 8;
    float* e_partial = v_acc + (size_t)N * 96;       // nAtomBlocks
    float* accum = e_partial + nAtomBlocks;          // 4
    int* counts = (int*)(accum + 4);                 // N
    int* rowptr = counts + N;                        // N+1
    int* cursor = rowptr + N + 1;                    // N
    int* order  = cursor + N;                        // E

    hipMemsetAsync(d_out, 0, (size_t)out_size * sizeof(float), stream);
    hipMemsetAsync(counts, 0, (size_t)N * sizeof(int), stream);
    hipMemsetAsync(accum, 0, 4 * sizeof(float), stream);

    hist_dst<<<2048, 256, 0, stream>>>(eidx, counts, E);
    scan_counts<<<1, 1024, 0, stream>>>(counts, rowptr, cursor, N);
    scatter_edges<<<2048, 256, 0, stream>>>(eidx, cursor, order, E);

    edge_fwd_gather<<<nAtomBlocks, 256, 0, stream>>>(pos, types, eidx, rowptr, order,
                                                     Wr1, br1, Wr2, temb,
                                                     s_acc, v_acc, N, E);
    atom_mlp<<<nAtomBlocks, 256, 0, stream>>>(types, temb, Wself, Wo1, bo1, Wo2,
                                              s_acc, v_acc, e_partial, N);
    reduce_energy<<<1, 256, 0, stream>>>(e_partial, nAtomBlocks, out);
    edge_bwd_gather<<<nAtomBlocks, 256, 0, stream>>>(pos, types, eidx, rowptr, order,
                                                     Wr1, br1, Wr2, temb,
                                                     s_acc, v_acc, forces, N, E);
    reduce_net<<<64, 256, 0, stream>>>(forces, masses, accum, N);
    correct_forces<<<(N + 255) / 256, 256, 0, stream>>>(forces, masses, accum, N);
}

// Round 3
// 1068.299 us; speedup vs baseline: 1.7272x; 1.7272x over previous
//
#include <hip/hip_runtime.h>
#include <math.h>

#define FDIM 32
#define NBASIS 8

constexpr float RCUT_C = 20.0f;
constexpr float PI_F = 3.14159265358979323846f;
constexpr float EV2KJ_C = 96.4853f;
constexpr float NM2A_C = 10.0f;

__device__ __forceinline__ float sigmoidf_(float z) { return 1.0f / (1.0f + __expf(-z)); }

// ---------------- CSR build: histogram, scan, scatter ----------------
__global__ __launch_bounds__(256) void hist_dst(
    const int* __restrict__ eidx, int* __restrict__ counts, int E)
{
    for (int e = blockIdx.x * 256 + threadIdx.x; e < E; e += gridDim.x * 256)
        atomicAdd(&counts[eidx[E + e]], 1);
}

__global__ __launch_bounds__(1024) void scan_counts(
    const int* __restrict__ counts, int* __restrict__ cursor, int N)
{
    __shared__ int lds[1024];
    const int t = threadIdx.x;
    const int chunk = (N + 1023) / 1024;
    const int start = t * chunk;
    const int end = min(start + chunk, N);
    int local = 0;
    for (int i = start; i < end; i++) local += counts[i];
    lds[t] = local;
    __syncthreads();
    for (int off = 1; off < 1024; off <<= 1) {
        int v = (t >= off) ? lds[t - off] : 0;
        __syncthreads();
        lds[t] += v;
        __syncthreads();
    }
    int run = lds[t] - local;  // exclusive prefix
    for (int i = start; i < end; i++) {
        cursor[i] = run;
        run += counts[i];
    }
}

__global__ __launch_bounds__(256) void scatter_edges(
    const int* __restrict__ eidx, int* __restrict__ cursor,
    int2* __restrict__ order_sd, int E)
{
    for (int e = blockIdx.x * 256 + threadIdx.x; e < E; e += gridDim.x * 256) {
        int dst = eidx[E + e];
        int p = atomicAdd(&cursor[dst], 1);
        order_sd[p] = make_int2(eidx[e], dst);
    }
}

// ---------------- edge forward (sorted edge-parallel + LDS run-merge) ----------------
__global__ __launch_bounds__(256) void edge_fwd_sorted(
    const float* __restrict__ pos, const int* __restrict__ types,
    const int2* __restrict__ order_sd,
    const float* __restrict__ Wr1, const float* __restrict__ br1,
    const float* __restrict__ Wr2, const float* __restrict__ temb,
    float* __restrict__ s_acc, float* __restrict__ v_acc, int E)
{
    __shared__ float mrg[8][128];
    __shared__ int mkey[8];

    const int lane = threadIdx.x & 31;
    const int g = threadIdx.x >> 5;        // half-wave id 0..7
    const int p = blockIdx.x * 8 + g;

    // weights -> VGPRs (uniform per lane, L1-resident)
    float w1r[NBASIS];
    #pragma unroll
    for (int n = 0; n < NBASIS; n++) w1r[n] = Wr1[n * FDIM + lane];
    const float b1 = br1[lane];
    float2 w2c[FDIM];
    #pragma unroll
    for (int f = 0; f < FDIM; f++)
        w2c[f] = make_float2(Wr2[f * 64 + lane], Wr2[f * 64 + 32 + lane]);
    const float te0 = temb[lane], te1 = temb[FDIM + lane], te2 = temb[2 * FDIM + lane];

    const bool valid = (p < E);
    int2 sd = valid ? order_sd[p] : make_int2(0, 0);

    float rx = (pos[sd.y * 3 + 0] - pos[sd.x * 3 + 0]) * NM2A_C;
    float ry = (pos[sd.y * 3 + 1] - pos[sd.x * 3 + 1]) * NM2A_C;
    float rz = (pos[sd.y * 3 + 2] - pos[sd.x * 3 + 2]) * NM2A_C;
    int tyi = types[sd.x];
    float r2 = rx * rx + ry * ry + rz * rz + 1e-12f;
    float r = sqrtf(r2);
    float rinv = 1.0f / r;
    float x = r * (1.0f / RCUT_C);
    float x2 = x * x, x4 = x2 * x2, x6 = x4 * x2, x7 = x6 * x, x8 = x6 * x2;
    float env = (x < 1.0f) ? (1.0f - 28.0f * x6 + 48.0f * x7 - 21.0f * x8) : 0.0f;

    float th = PI_F * x, s1, c1;
    __sincosf(th, &s1, &c1);
    float sp = 0.0f, sn = s1;
    float z = b1;
    #pragma unroll
    for (int n = 0; n < NBASIS; n++) {
        z += (sn * rinv) * w1r[n];
        float snx = 2.0f * c1 * sn - sp; sp = sn; sn = snx;
    }
    float sg = sigmoidf_(z);
    float q = z * sg;

    float rw0 = 0.0f, rw1 = 0.0f;
    #pragma unroll
    for (int f = 0; f < FDIM; f++) {
        float qv = __shfl(q, f, 32);
        rw0 += qv * w2c[f].x;
        rw1 += qv * w2c[f].y;
    }
    float hs = (tyi == 0) ? te0 : ((tyi == 1) ? te1 : te2);
    float s_sum = hs * rw0 * env;
    float hw1 = hs * rw1 * env;

    mrg[g][lane]       = s_sum;
    mrg[g][32 + lane]  = hw1 * rx * rinv;
    mrg[g][64 + lane]  = hw1 * ry * rinv;
    mrg[g][96 + lane]  = hw1 * rz * rinv;
    if (lane == 0) mkey[g] = valid ? sd.y : -1;
    __syncthreads();

    if (threadIdx.x < 128) {
        const int col = threadIdx.x;
        float acc = 0.0f; int key = -1;
        #pragma unroll
        for (int row = 0; row < 8; row++) {
            int k = mkey[row];
            float val = mrg[row][col];
            if (k != key) {
                if (key >= 0) {
                    if (col < 32) unsafeAtomicAdd(&s_acc[(size_t)key * 32 + col], acc);
                    else          unsafeAtomicAdd(&v_acc[(size_t)key * 96 + (col - 32)], acc);
                }
                key = k; acc = val;
            } else acc += val;
        }
        if (key >= 0) {
            if (col < 32) unsafeAtomicAdd(&s_acc[(size_t)key * 32 + col], acc);
            else          unsafeAtomicAdd(&v_acc[(size_t)key * 96 + (col - 32)], acc);
        }
    }
}

// -------- atom MLP: energy partials + g_s/g_v (in-place over s/v) --------
__global__ __launch_bounds__(256) void atom_mlp(
    const int* __restrict__ types, const float* __restrict__ temb,
    const float* __restrict__ Wself, const float* __restrict__ Wo1,
    const float* __restrict__ bo1, const float* __restrict__ Wo2,
    float* __restrict__ s_acc, float* __restrict__ v_acc,
    float* __restrict__ e_partial, int N)
{
    __shared__ float sWs[FDIM * FDIM], sWsT[FDIM * FDIM];
    __shared__ float sWo1[2 * FDIM * FDIM], sWo1T[2 * FDIM * FDIM];
    __shared__ float sb[FDIM], sW2o[FDIM], sTE[96];
    __shared__ float gred[8];
    for (int i = threadIdx.x; i < FDIM * FDIM; i += 256) {
        sWs[i] = Wself[i];
        sWsT[i] = Wself[(i & 31) * FDIM + (i >> 5)];
    }
    for (int i = threadIdx.x; i < 2 * FDIM * FDIM; i += 256) {
        sWo1[i] = Wo1[i];
        sWo1T[i] = Wo1[(i & 63) * FDIM + (i >> 6)];
    }
    for (int i = threadIdx.x; i < FDIM; i += 256) { sb[i] = bo1[i]; sW2o[i] = Wo2[i]; }
    for (int i = threadIdx.x; i < 96; i += 256) sTE[i] = temb[i];
    __syncthreads();

    const int lane = threadIdx.x & 31;
    const int g = threadIdx.x >> 5;
    int a = blockIdx.x * 8 + g;
    const bool valid = (a < N);
    if (!valid) a = 0;

    float sv = s_acc[(size_t)a * FDIM + lane];
    float vx = v_acc[(size_t)a * 96 + 0 * 32 + lane];
    float vy = v_acc[(size_t)a * 96 + 1 * 32 + lane];
    float vz = v_acc[(size_t)a * 96 + 2 * 32 + lane];
    float h = sTE[types[a] * FDIM + lane];
    float vn = sqrtf(vx * vx + vy * vy + vz * vz + 1e-12f);

    float row = h;
    #pragma unroll
    for (int f = 0; f < FDIM; f++) {
        float t = __shfl(sv, f, 32);
        row += t * sWs[f * FDIM + lane];
    }
    float u = sb[lane];
    #pragma unroll
    for (int j = 0; j < FDIM; j++) {
        float rv = __shfl(row, j, 32);
        float vv = __shfl(vn, j, 32);
        u += rv * sWo1[j * FDIM + lane] + vv * sWo1[(j + FDIM) * FDIM + lane];
    }
    float sg = sigmoidf_(u);
    float au = u * sg;
    float pa = valid ? au * sW2o[lane] : 0.0f;
    #pragma unroll
    for (int m = 16; m; m >>= 1) pa += __shfl_xor(pa, m, 32);
    if (lane == 0) gred[g] = pa;

    float gu = sW2o[lane] * (sg * (1.0f + u * (1.0f - sg)));
    float gfr = 0.0f, gfv = 0.0f;
    #pragma unroll
    for (int k = 0; k < FDIM; k++) {
        float gv_ = __shfl(gu, k, 32);
        gfr += gv_ * sWo1T[k * 64 + lane];
        gfv += gv_ * sWo1T[k * 64 + 32 + lane];
    }
    float gs = 0.0f;
    #pragma unroll
    for (int k = 0; k < FDIM; k++) {
        float gr = __shfl(gfr, k, 32);
        gs += gr * sWsT[k * FDIM + lane];
    }
    __syncthreads();
    if (valid) {
        s_acc[(size_t)a * FDIM + lane] = gs;
        float sc = gfv / vn;
        v_acc[(size_t)a * 96 + 0 * 32 + lane] = sc * vx;
        v_acc[(size_t)a * 96 + 1 * 32 + lane] = sc * vy;
        v_acc[(size_t)a * 96 + 2 * 32 + lane] = sc * vz;
    }
    if (threadIdx.x == 0) {
        float t = 0.0f;
        #pragma unroll
        for (int i = 0; i < 8; i++) t += gred[i];
        e_partial[blockIdx.x] = t;
    }
}

// ---------------- edge backward (sorted edge-parallel, u-trick, LDS merge) ----------------
__global__ __launch_bounds__(256) void edge_bwd_sorted(
    const float* __restrict__ pos, const int* __restrict__ types,
    const int2* __restrict__ order_sd,
    const float* __restrict__ Wr1, const float* __restrict__ br1,
    const float* __restrict__ Wr2, const float* __restrict__ temb,
    const float* __restrict__ g_s, const float* __restrict__ g_v,
    float* __restrict__ forces, int E)
{
    __shared__ float mrgF[8][4];
    __shared__ int mkey[8];

    const int lane = threadIdx.x & 31;
    const int g = threadIdx.x >> 5;
    const int p = blockIdx.x * 8 + g;

    float w1r[NBASIS];
    #pragma unroll
    for (int n = 0; n < NBASIS; n++) w1r[n] = Wr1[n * FDIM + lane];
    const float b1 = br1[lane];
    float2 w2c[FDIM];
    #pragma unroll
    for (int f = 0; f < FDIM; f++)
        w2c[f] = make_float2(Wr2[f * 64 + lane], Wr2[f * 64 + 32 + lane]);
    const float te0 = temb[lane], te1 = temb[FDIM + lane], te2 = temb[2 * FDIM + lane];

    const bool valid = (p < E);
    int2 sd = valid ? order_sd[p] : make_int2(0, 0);

    float rx = (pos[sd.y * 3 + 0] - pos[sd.x * 3 + 0]) * NM2A_C;
    float ry = (pos[sd.y * 3 + 1] - pos[sd.x * 3 + 1]) * NM2A_C;
    float rz = (pos[sd.y * 3 + 2] - pos[sd.x * 3 + 2]) * NM2A_C;
    int tyi = types[sd.x];
    float gm0  = g_s[(size_t)sd.y * FDIM + lane];
    float gm1x = g_v[(size_t)sd.y * 96 + 0 * 32 + lane];
    float gm1y = g_v[(size_t)sd.y * 96 + 1 * 32 + lane];
    float gm1z = g_v[(size_t)sd.y * 96 + 2 * 32 + lane];

    float r2 = rx * rx + ry * ry + rz * rz + 1e-12f;
    float r = sqrtf(r2);
    float rinv = 1.0f / r;
    float x = r * (1.0f / RCUT_C);
    float x2 = x * x, x4 = x2 * x2, x5 = x4 * x, x6 = x4 * x2, x7 = x6 * x, x8 = x6 * x2;
    float env = (x < 1.0f) ? (1.0f - 28.0f * x6 + 48.0f * x7 - 21.0f * x8) : 0.0f;
    float denv = (x < 1.0f) ? (-168.0f * x5 + 336.0f * x6 - 168.0f * x7) * (1.0f / RCUT_C) : 0.0f;

    float th = PI_F * x, s1, c1;
    __sincosf(th, &s1, &c1);
    float sp = 0.0f, sn = s1, cp = 1.0f, cn = c1;
    float z = b1;
    float tacc = 0.0f;
    #pragma unroll
    for (int n = 0; n < NBASIS; n++) {
        float basis = sn * rinv;
        z += basis * w1r[n];
        float dbdr = (PI_F * (float)(n + 1) * (1.0f / RCUT_C)) * cn * rinv - basis * rinv;
        tacc += dbdr * w1r[n];
        float snx = 2.0f * c1 * sn - sp; sp = sn; sn = snx;
        float cnx = 2.0f * c1 * cn - cp; cp = cn; cn = cnx;
    }
    float sg = sigmoidf_(z);
    float q = z * sg;
    float tf = (sg * (1.0f + z * (1.0f - sg))) * tacc;   // silu' * d z/dr weight

    float rw0 = 0.0f, rw1 = 0.0f, u0 = 0.0f, u1 = 0.0f;
    #pragma unroll
    for (int f = 0; f < FDIM; f++) {
        float qv = __shfl(q, f, 32);
        float tv = __shfl(tf, f, 32);
        rw0 += qv * w2c[f].x;
        rw1 += qv * w2c[f].y;
        u0  += tv * w2c[f].x;
        u1  += tv * w2c[f].y;
    }
    float hs = (tyi == 0) ? te0 : ((tyi == 1) ? te1 : te2);
    float rhx = rx * rinv, rhy = ry * rinv, rhz = rz * rinv;
    float gw0 = hs * gm0;
    float gw1 = hs * (gm1x * rhx + gm1y * rhy + gm1z * rhz);
    float hw1 = hs * rw1 * env;
    float grx = hw1 * gm1x, gry = hw1 * gm1y, grz = hw1 * gm1z;
    float genv = gw0 * rw0 + gw1 * rw1;
    // per-lane partial of dE/dr: basis path (u-trick) + envelope path
    float pc = (gw0 * env) * u0 + (gw1 * env) * u1 + genv * denv;

    #pragma unroll
    for (int m = 16; m; m >>= 1) {
        grx += __shfl_xor(grx, m, 32);
        gry += __shfl_xor(gry, m, 32);
        grz += __shfl_xor(grz, m, 32);
        pc  += __shfl_xor(pc, m, 32);
    }

    float dotg = grx * rhx + gry * rhy + grz * rhz;
    float gex = pc * rhx + (grx - dotg * rhx) * rinv;
    float gey = pc * rhy + (gry - dotg * rhy) * rinv;
    float gez = pc * rhz + (grz - dotg * rhz) * rinv;

    const float SC = EV2KJ_C * NM2A_C;
    if (lane < 3) {
        float comp = (lane == 0) ? gex : ((lane == 1) ? gey : gez);
        if (valid) unsafeAtomicAdd(&forces[(size_t)sd.x * 3 + lane], SC * comp);
        mrgF[g][lane] = comp;
    }
    if (lane == 0) mkey[g] = valid ? sd.y : -1;
    __syncthreads();

    if (threadIdx.x < 3) {
        const int c = threadIdx.x;
        float acc = 0.0f; int key = -1;
        #pragma unroll
        for (int row = 0; row < 8; row++) {
            int k = mkey[row];
            float val = mrgF[row][c];
            if (k != key) {
                if (key >= 0) unsafeAtomicAdd(&forces[(size_t)key * 3 + c], -SC * acc);
                key = k; acc = val;
            } else acc += val;
        }
        if (key >= 0) unsafeAtomicAdd(&forces[(size_t)key * 3 + c], -SC * acc);
    }
}

// ---------------- reductions & correction ----------------
__global__ __launch_bounds__(256) void reduce_energy(
    const float* __restrict__ e_partial, int n, float* __restrict__ out)
{
    __shared__ float red[256];
    float s = 0.0f;
    for (int i = threadIdx.x; i < n; i += 256) s += e_partial[i];
    red[threadIdx.x] = s;
    __syncthreads();
    for (int k = 128; k; k >>= 1) {
        if (threadIdx.x < k) red[threadIdx.x] += red[threadIdx.x + k];
        __syncthreads();
    }
    if (threadIdx.x == 0) out[0] = red[0] * EV2KJ_C;
}

__global__ __launch_bounds__(256) void reduce_net(
    const float* __restrict__ f, const float* __restrict__ masses,
    float* __restrict__ accum, int N)
{
    float nx = 0, ny = 0, nz = 0, ms = 0;
    for (int i = blockIdx.x * 256 + threadIdx.x; i < N; i += gridDim.x * 256) {
        nx += f[i * 3 + 0]; ny += f[i * 3 + 1]; nz += f[i * 3 + 2]; ms += masses[i];
    }
    #pragma unroll
    for (int m = 32; m; m >>= 1) {
        nx += __shfl_xor(nx, m, 64);
        ny += __shfl_xor(ny, m, 64);
        nz += __shfl_xor(nz, m, 64);
        ms += __shfl_xor(ms, m, 64);
    }
    __shared__ float red[4][4];
    int w = threadIdx.x >> 6;
    if ((threadIdx.x & 63) == 0) { red[w][0] = nx; red[w][1] = ny; red[w][2] = nz; red[w][3] = ms; }
    __syncthreads();
    if (threadIdx.x == 0) {
        float a0 = 0, a1 = 0, a2 = 0, a3 = 0;
        for (int i = 0; i < 4; i++) { a0 += red[i][0]; a1 += red[i][1]; a2 += red[i][2]; a3 += red[i][3]; }
        unsafeAtomicAdd(accum + 0, a0);
        unsafeAtomicAdd(accum + 1, a1);
        unsafeAtomicAdd(accum + 2, a2);
        unsafeAtomicAdd(accum + 3, a3);
    }
}

__global__ __launch_bounds__(256) void correct_forces(
    float* __restrict__ f, const float* __restrict__ masses,
    const float* __restrict__ accum, int N)
{
    int i = blockIdx.x * 256 + threadIdx.x;
    if (i < N) {
        float c = masses[i] / accum[3];
        f[i * 3 + 0] -= c * accum[0];
        f[i * 3 + 1] -= c * accum[1];
        f[i * 3 + 2] -= c * accum[2];
    }
}

extern "C" void kernel_launch(void* const* d_in, const int* in_sizes, int n_in,
                              void* d_out, int out_size, void* d_ws, size_t ws_size,
                              hipStream_t stream)
{
    (void)n_in; (void)ws_size;
    const float* pos    = (const float*)d_in[0];
    const float* masses = (const float*)d_in[1];
    const float* temb   = (const float*)d_in[2];
    const float* Wr1    = (const float*)d_in[3];
    const float* br1    = (const float*)d_in[4];
    const float* Wr2    = (const float*)d_in[5];
    const float* Wself  = (const float*)d_in[6];
    const float* Wo1    = (const float*)d_in[7];
    const float* bo1    = (const float*)d_in[8];
    const float* Wo2    = (const float*)d_in[9];
    const int* types    = (const int*)d_in[10];
    const int* eidx     = (const int*)d_in[11];
    const int N = in_sizes[1];
    const int E = in_sizes[11] / 2;

    float* out = (float*)d_out;
    float* forces = out + 1;

    float* ws = (float*)d_ws;
    float* s_acc = ws;                               // N*32
    float* v_acc = s_acc + (size_t)N * FDIM;         // N*96
    int nAtomBlocks = (N + 7) / 8;
    float* e_partial = v_acc + (size_t)N * 96;       // nAtomBlocks
    float* accum = e_partial + nAtomBlocks;          // 4
    int* counts = (int*)(accum + 4);                 // N
    int* cursor = counts + N;                        // N
    int2* order_sd = (int2*)(cursor + N);            // E int2

    hipMemsetAsync(d_out, 0, (size_t)out_size * sizeof(float), stream);
    hipMemsetAsync(s_acc, 0, (size_t)N * 128 * sizeof(float), stream);
    hipMemsetAsync(counts, 0, (size_t)N * sizeof(int), stream);
    hipMemsetAsync(accum, 0, 4 * sizeof(float), stream);

    hist_dst<<<2048, 256, 0, stream>>>(eidx, counts, E);
    scan_counts<<<1, 1024, 0, stream>>>(counts, cursor, N);
    scatter_edges<<<2048, 256, 0, stream>>>(eidx, cursor, order_sd, E);

    int nEdgeBlocks = (E + 7) / 8;
    edge_fwd_sorted<<<nEdgeBlocks, 256, 0, stream>>>(pos, types, order_sd,
                                                     Wr1, br1, Wr2, temb,
                                                     s_acc, v_acc, E);
    atom_mlp<<<nAtomBlocks, 256, 0, stream>>>(types, temb, Wself, Wo1, bo1, Wo2,
                                              s_acc, v_acc, e_partial, N);
    reduce_energy<<<1, 256, 0, stream>>>(e_partial, nAtomBlocks, out);
    edge_bwd_sorted<<<nEdgeBlocks, 256, 0, stream>>>(pos, types, order_sd,
                                                     Wr1, br1, Wr2, temb,
                                                     s_acc, v_acc, forces, E);
    reduce_net<<<64, 256, 0, stream>>>(forces, masses, accum, N);
    correct_forces<<<(N + 255) / 256, 256, 0, stream>>>(forces, masses, accum, N);
}

// Round 4
// 1022.255 us; speedup vs baseline: 1.8050x; 1.0450x over previous
//
#include <hip/hip_runtime.h>
#include <math.h>

#define FDIM 32
#define NBASIS 8
#define CHUNK 64          // edges per block
#define ITERS 8           // CHUNK / 8 half-waves

constexpr float RCUT_C = 20.0f;
constexpr float PI_F = 3.14159265358979323846f;
constexpr float EV2KJ_C = 96.4853f;
constexpr float NM2A_C = 10.0f;

__device__ __forceinline__ float sigmoidf_(float z) { return 1.0f / (1.0f + __expf(-z)); }

// ---------------- CSR build: histogram, scan, scatter ----------------
__global__ __launch_bounds__(256) void hist_dst(
    const int* __restrict__ eidx, int* __restrict__ counts, int E)
{
    for (int e = blockIdx.x * 256 + threadIdx.x; e < E; e += gridDim.x * 256)
        atomicAdd(&counts[eidx[E + e]], 1);
}

__global__ __launch_bounds__(1024) void scan_counts(
    const int* __restrict__ counts, int* __restrict__ cursor, int N)
{
    __shared__ int lds[1024];
    const int t = threadIdx.x;
    const int chunk = (N + 1023) / 1024;
    const int start = t * chunk;
    const int end = min(start + chunk, N);
    int local = 0;
    for (int i = start; i < end; i++) local += counts[i];
    lds[t] = local;
    __syncthreads();
    for (int off = 1; off < 1024; off <<= 1) {
        int v = (t >= off) ? lds[t - off] : 0;
        __syncthreads();
        lds[t] += v;
        __syncthreads();
    }
    int run = lds[t] - local;
    for (int i = start; i < end; i++) {
        cursor[i] = run;
        run += counts[i];
    }
}

__global__ __launch_bounds__(256) void scatter_edges(
    const int* __restrict__ eidx, int* __restrict__ cursor,
    int2* __restrict__ order_sd, int E)
{
    for (int e = blockIdx.x * 256 + threadIdx.x; e < E; e += gridDim.x * 256) {
        int dst = eidx[E + e];
        int p = atomicAdd(&cursor[dst], 1);
        order_sd[p] = make_int2(eidx[e], dst);
    }
}

// ---------------- edge forward (chunked, sorted, run-carrying merge) ----------------
__global__ __launch_bounds__(256, 2) void edge_fwd_sorted(
    const float* __restrict__ pos, const int* __restrict__ types,
    const int2* __restrict__ order_sd,
    const float* __restrict__ Wr1, const float* __restrict__ br1,
    const float* __restrict__ Wr2, const float* __restrict__ temb,
    float* __restrict__ s_acc, float* __restrict__ v_acc, int E)
{
    __shared__ float mrg[2][8][128];
    __shared__ int mkeyA[2][8];

    const int lane = threadIdx.x & 31;
    const int g = threadIdx.x >> 5;
    const int tid = threadIdx.x;
    const int base = blockIdx.x * CHUNK;

    // weights -> VGPRs, once per block
    float w1r[NBASIS];
    #pragma unroll
    for (int n = 0; n < NBASIS; n++) w1r[n] = Wr1[n * FDIM + lane];
    const float b1 = br1[lane];
    float2 w2c[FDIM];
    #pragma unroll
    for (int f = 0; f < FDIM; f++)
        w2c[f] = make_float2(Wr2[f * 64 + lane], Wr2[f * 64 + 32 + lane]);
    const float te0 = temb[lane], te1 = temb[FDIM + lane], te2 = temb[2 * FDIM + lane];

    // run-carrying merge state (threads 0..127)
    int runKey = -1;
    float runAcc = 0.0f;

    for (int it = 0; it < ITERS; it++) {
        const int p = base + it * 8 + g;
        const bool valid = (p < E);
        int2 sd = valid ? order_sd[p] : make_int2(0, 0);

        float rx = (pos[sd.y * 3 + 0] - pos[sd.x * 3 + 0]) * NM2A_C;
        float ry = (pos[sd.y * 3 + 1] - pos[sd.x * 3 + 1]) * NM2A_C;
        float rz = (pos[sd.y * 3 + 2] - pos[sd.x * 3 + 2]) * NM2A_C;
        int tyi = types[sd.x];
        float r2 = rx * rx + ry * ry + rz * rz + 1e-12f;
        float r = sqrtf(r2);
        float rinv = 1.0f / r;
        float x = r * (1.0f / RCUT_C);
        float x2 = x * x, x4 = x2 * x2, x6 = x4 * x2, x7 = x6 * x, x8 = x6 * x2;
        float env = (x < 1.0f) ? (1.0f - 28.0f * x6 + 48.0f * x7 - 21.0f * x8) : 0.0f;

        float th = PI_F * x, s1, c1;
        __sincosf(th, &s1, &c1);
        float sp = 0.0f, sn = s1;
        float z = b1;
        #pragma unroll
        for (int n = 0; n < NBASIS; n++) {
            z += (sn * rinv) * w1r[n];
            float snx = 2.0f * c1 * sn - sp; sp = sn; sn = snx;
        }
        float sg = sigmoidf_(z);
        float q = z * sg;

        float rw0 = 0.0f, rw1 = 0.0f;
        #pragma unroll
        for (int f = 0; f < FDIM; f++) {
            float qv = __shfl(q, f, 32);
            rw0 += qv * w2c[f].x;
            rw1 += qv * w2c[f].y;
        }
        float hs = (tyi == 0) ? te0 : ((tyi == 1) ? te1 : te2);
        float s_sum = hs * rw0 * env;
        float hw1 = hs * rw1 * env;

        const int buf = it & 1;
        mrg[buf][g][lane]      = s_sum;
        mrg[buf][g][32 + lane] = hw1 * rx * rinv;
        mrg[buf][g][64 + lane] = hw1 * ry * rinv;
        mrg[buf][g][96 + lane] = hw1 * rz * rinv;
        if (lane == 0) mkeyA[buf][g] = valid ? sd.y : -1;
        __syncthreads();

        if (tid < 128) {
            #pragma unroll
            for (int row = 0; row < 8; row++) {
                int k = mkeyA[buf][row];
                float val = mrg[buf][row][tid];
                if (k != runKey) {
                    if (runKey >= 0) {
                        if (tid < 32) unsafeAtomicAdd(&s_acc[(size_t)runKey * 32 + tid], runAcc);
                        else          unsafeAtomicAdd(&v_acc[(size_t)runKey * 96 + (tid - 32)], runAcc);
                    }
                    runKey = k; runAcc = val;
                } else runAcc += val;
            }
        }
        // ping-pong: next iter writes the other buffer; writes to THIS buffer
        // happen only after the next __syncthreads, by which time merge is done.
    }
    if (tid < 128 && runKey >= 0) {
        if (tid < 32) unsafeAtomicAdd(&s_acc[(size_t)runKey * 32 + tid], runAcc);
        else          unsafeAtomicAdd(&v_acc[(size_t)runKey * 96 + (tid - 32)], runAcc);
    }
}

// -------- atom MLP: energy partials + g_s/g_v (in-place over s/v) --------
__global__ __launch_bounds__(256) void atom_mlp(
    const int* __restrict__ types, const float* __restrict__ temb,
    const float* __restrict__ Wself, const float* __restrict__ Wo1,
    const float* __restrict__ bo1, const float* __restrict__ Wo2,
    float* __restrict__ s_acc, float* __restrict__ v_acc,
    float* __restrict__ e_partial, int N)
{
    __shared__ float sWs[FDIM * FDIM], sWsT[FDIM * FDIM];
    __shared__ float sWo1[2 * FDIM * FDIM], sWo1T[2 * FDIM * FDIM];
    __shared__ float sb[FDIM], sW2o[FDIM], sTE[96];
    __shared__ float gred[8];
    for (int i = threadIdx.x; i < FDIM * FDIM; i += 256) {
        sWs[i] = Wself[i];
        sWsT[i] = Wself[(i & 31) * FDIM + (i >> 5)];
    }
    for (int i = threadIdx.x; i < 2 * FDIM * FDIM; i += 256) {
        sWo1[i] = Wo1[i];
        sWo1T[i] = Wo1[(i & 63) * FDIM + (i >> 6)];
    }
    for (int i = threadIdx.x; i < FDIM; i += 256) { sb[i] = bo1[i]; sW2o[i] = Wo2[i]; }
    for (int i = threadIdx.x; i < 96; i += 256) sTE[i] = temb[i];
    __syncthreads();

    const int lane = threadIdx.x & 31;
    const int g = threadIdx.x >> 5;
    int a = blockIdx.x * 8 + g;
    const bool valid = (a < N);
    if (!valid) a = 0;

    float sv = s_acc[(size_t)a * FDIM + lane];
    float vx = v_acc[(size_t)a * 96 + 0 * 32 + lane];
    float vy = v_acc[(size_t)a * 96 + 1 * 32 + lane];
    float vz = v_acc[(size_t)a * 96 + 2 * 32 + lane];
    float h = sTE[types[a] * FDIM + lane];
    float vn = sqrtf(vx * vx + vy * vy + vz * vz + 1e-12f);

    float row = h;
    #pragma unroll
    for (int f = 0; f < FDIM; f++) {
        float t = __shfl(sv, f, 32);
        row += t * sWs[f * FDIM + lane];
    }
    float u = sb[lane];
    #pragma unroll
    for (int j = 0; j < FDIM; j++) {
        float rv = __shfl(row, j, 32);
        float vv = __shfl(vn, j, 32);
        u += rv * sWo1[j * FDIM + lane] + vv * sWo1[(j + FDIM) * FDIM + lane];
    }
    float sg = sigmoidf_(u);
    float au = u * sg;
    float pa = valid ? au * sW2o[lane] : 0.0f;
    #pragma unroll
    for (int m = 16; m; m >>= 1) pa += __shfl_xor(pa, m, 32);
    if (lane == 0) gred[g] = pa;

    float gu = sW2o[lane] * (sg * (1.0f + u * (1.0f - sg)));
    float gfr = 0.0f, gfv = 0.0f;
    #pragma unroll
    for (int k = 0; k < FDIM; k++) {
        float gv_ = __shfl(gu, k, 32);
        gfr += gv_ * sWo1T[k * 64 + lane];
        gfv += gv_ * sWo1T[k * 64 + 32 + lane];
    }
    float gs = 0.0f;
    #pragma unroll
    for (int k = 0; k < FDIM; k++) {
        float gr = __shfl(gfr, k, 32);
        gs += gr * sWsT[k * FDIM + lane];
    }
    __syncthreads();
    if (valid) {
        s_acc[(size_t)a * FDIM + lane] = gs;
        float sc = gfv / vn;
        v_acc[(size_t)a * 96 + 0 * 32 + lane] = sc * vx;
        v_acc[(size_t)a * 96 + 1 * 32 + lane] = sc * vy;
        v_acc[(size_t)a * 96 + 2 * 32 + lane] = sc * vz;
    }
    if (threadIdx.x == 0) {
        float t = 0.0f;
        #pragma unroll
        for (int i = 0; i < 8; i++) t += gred[i];
        e_partial[blockIdx.x] = t;
    }
}

// ---------------- edge backward (chunked, u-trick, channel butterfly) ----------------
__global__ __launch_bounds__(256, 2) void edge_bwd_sorted(
    const float* __restrict__ pos, const int* __restrict__ types,
    const int2* __restrict__ order_sd,
    const float* __restrict__ Wr1, const float* __restrict__ br1,
    const float* __restrict__ Wr2, const float* __restrict__ temb,
    const float* __restrict__ g_s, const float* __restrict__ g_v,
    float* __restrict__ forces, int E)
{
    __shared__ float mrgF[2][8][4];
    __shared__ int mkeyA[2][8];

    const int lane = threadIdx.x & 31;
    const int g = threadIdx.x >> 5;
    const int tid = threadIdx.x;
    const int base = blockIdx.x * CHUNK;

    float w1r[NBASIS];
    #pragma unroll
    for (int n = 0; n < NBASIS; n++) w1r[n] = Wr1[n * FDIM + lane];
    const float b1 = br1[lane];
    float2 w2c[FDIM];
    #pragma unroll
    for (int f = 0; f < FDIM; f++)
        w2c[f] = make_float2(Wr2[f * 64 + lane], Wr2[f * 64 + 32 + lane]);
    const float te0 = temb[lane], te1 = temb[FDIM + lane], te2 = temb[2 * FDIM + lane];

    const float SC = EV2KJ_C * NM2A_C;
    int runKey = -1;
    float runAcc = 0.0f;

    for (int it = 0; it < ITERS; it++) {
        const int p = base + it * 8 + g;
        const bool valid = (p < E);
        int2 sd = valid ? order_sd[p] : make_int2(0, 0);

        float rx = (pos[sd.y * 3 + 0] - pos[sd.x * 3 + 0]) * NM2A_C;
        float ry = (pos[sd.y * 3 + 1] - pos[sd.x * 3 + 1]) * NM2A_C;
        float rz = (pos[sd.y * 3 + 2] - pos[sd.x * 3 + 2]) * NM2A_C;
        int tyi = types[sd.x];
        float gm0  = g_s[(size_t)sd.y * FDIM + lane];
        float gm1x = g_v[(size_t)sd.y * 96 + 0 * 32 + lane];
        float gm1y = g_v[(size_t)sd.y * 96 + 1 * 32 + lane];
        float gm1z = g_v[(size_t)sd.y * 96 + 2 * 32 + lane];

        float r2 = rx * rx + ry * ry + rz * rz + 1e-12f;
        float r = sqrtf(r2);
        float rinv = 1.0f / r;
        float x = r * (1.0f / RCUT_C);
        float x2 = x * x, x4 = x2 * x2, x5 = x4 * x, x6 = x4 * x2, x7 = x6 * x, x8 = x6 * x2;
        float env = (x < 1.0f) ? (1.0f - 28.0f * x6 + 48.0f * x7 - 21.0f * x8) : 0.0f;
        float denv = (x < 1.0f) ? (-168.0f * x5 + 336.0f * x6 - 168.0f * x7) * (1.0f / RCUT_C) : 0.0f;

        float th = PI_F * x, s1, c1;
        __sincosf(th, &s1, &c1);
        float sp = 0.0f, sn = s1, cp = 1.0f, cn = c1;
        float z = b1;
        float tacc = 0.0f;
        #pragma unroll
        for (int n = 0; n < NBASIS; n++) {
            float basis = sn * rinv;
            z += basis * w1r[n];
            float dbdr = (PI_F * (float)(n + 1) * (1.0f / RCUT_C)) * cn * rinv - basis * rinv;
            tacc += dbdr * w1r[n];
            float snx = 2.0f * c1 * sn - sp; sp = sn; sn = snx;
            float cnx = 2.0f * c1 * cn - cp; cp = cn; cn = cnx;
        }
        float sg = sigmoidf_(z);
        float q = z * sg;
        float tf = (sg * (1.0f + z * (1.0f - sg))) * tacc;

        float rw0 = 0.0f, rw1 = 0.0f, u0 = 0.0f, u1 = 0.0f;
        #pragma unroll
        for (int f = 0; f < FDIM; f++) {
            float qv = __shfl(q, f, 32);
            float tv = __shfl(tf, f, 32);
            rw0 += qv * w2c[f].x;
            rw1 += qv * w2c[f].y;
            u0  += tv * w2c[f].x;
            u1  += tv * w2c[f].y;
        }
        float hs = (tyi == 0) ? te0 : ((tyi == 1) ? te1 : te2);
        float rhx = rx * rinv, rhy = ry * rinv, rhz = rz * rinv;
        float gw0 = hs * gm0;
        float gw1 = hs * (gm1x * rhx + gm1y * rhy + gm1z * rhz);
        float hw1 = hs * rw1 * env;
        float grx = hw1 * gm1x, gry = hw1 * gm1y, grz = hw1 * gm1z;
        float genv = gw0 * rw0 + gw1 * rw1;
        float pc = (gw0 * env) * u0 + (gw1 * env) * u1 + genv * denv;
        // per-lane scalar channel: beta contribution
        float pg = pc - (grx * rhx + gry * rhy + grz * rhz) * rinv;

        // channel-packed butterfly: 9 shfls -> lane&3 holds {Gx,Gy,Gz,beta}
        float a1 = grx + __shfl_xor(grx, 1, 32);
        float b1v = gry + __shfl_xor(gry, 1, 32);
        float c1v = grz + __shfl_xor(grz, 1, 32);
        float d1 = pg + __shfl_xor(pg, 1, 32);
        float e0 = (lane & 1) ? b1v : a1;
        float e1 = (lane & 1) ? d1 : c1v;
        e0 += __shfl_xor(e0, 2, 32);
        e1 += __shfl_xor(e1, 2, 32);
        float v = (lane & 2) ? e1 : e0;
        v += __shfl_xor(v, 4, 32);
        v += __shfl_xor(v, 8, 32);
        v += __shfl_xor(v, 16, 32);
        float beta = __shfl(v, lane | 3, 32);

        const int buf = it & 1;
        if (lane < 3) {
            float rh_l = (lane == 0) ? rhx : ((lane == 1) ? rhy : rhz);
            float comp = v * rinv + rh_l * beta;
            if (valid) unsafeAtomicAdd(&forces[(size_t)sd.x * 3 + lane], SC * comp);
            mrgF[buf][g][lane] = comp;
        }
        if (lane == 0) mkeyA[buf][g] = valid ? sd.y : -1;
        __syncthreads();

        if (tid < 3) {
            #pragma unroll
            for (int row = 0; row < 8; row++) {
                int k = mkeyA[buf][row];
                float val = mrgF[buf][row][tid];
                if (k != runKey) {
                    if (runKey >= 0)
                        unsafeAtomicAdd(&forces[(size_t)runKey * 3 + tid], -SC * runAcc);
                    runKey = k; runAcc = val;
                } else runAcc += val;
            }
        }
    }
    if (tid < 3 && runKey >= 0)
        unsafeAtomicAdd(&forces[(size_t)runKey * 3 + tid], -SC * runAcc);
}

// ---------------- reductions & correction ----------------
__global__ __launch_bounds__(256) void reduce_energy(
    const float* __restrict__ e_partial, int n, float* __restrict__ out)
{
    __shared__ float red[256];
    float s = 0.0f;
    for (int i = threadIdx.x; i < n; i += 256) s += e_partial[i];
    red[threadIdx.x] = s;
    __syncthreads();
    for (int k = 128; k; k >>= 1) {
        if (threadIdx.x < k) red[threadIdx.x] += red[threadIdx.x + k];
        __syncthreads();
    }
    if (threadIdx.x == 0) out[0] = red[0] * EV2KJ_C;
}

__global__ __launch_bounds__(256) void reduce_net(
    const float* __restrict__ f, const float* __restrict__ masses,
    float* __restrict__ accum, int N)
{
    float nx = 0, ny = 0, nz = 0, ms = 0;
    for (int i = blockIdx.x * 256 + threadIdx.x; i < N; i += gridDim.x * 256) {
        nx += f[i * 3 + 0]; ny += f[i * 3 + 1]; nz += f[i * 3 + 2]; ms += masses[i];
    }
    #pragma unroll
    for (int m = 32; m; m >>= 1) {
        nx += __shfl_xor(nx, m, 64);
        ny += __shfl_xor(ny, m, 64);
        nz += __shfl_xor(nz, m, 64);
        ms += __shfl_xor(ms, m, 64);
    }
    __shared__ float red[4][4];
    int w = threadIdx.x >> 6;
    if ((threadIdx.x & 63) == 0) { red[w][0] = nx; red[w][1] = ny; red[w][2] = nz; red[w][3] = ms; }
    __syncthreads();
    if (threadIdx.x == 0) {
        float a0 = 0, a1 = 0, a2 = 0, a3 = 0;
        for (int i = 0; i < 4; i++) { a0 += red[i][0]; a1 += red[i][1]; a2 += red[i][2]; a3 += red[i][3]; }
        unsafeAtomicAdd(accum + 0, a0);
        unsafeAtomicAdd(accum + 1, a1);
        unsafeAtomicAdd(accum + 2, a2);
        unsafeAtomicAdd(accum + 3, a3);
    }
}

__global__ __launch_bounds__(256) void correct_forces(
    float* __restrict__ f, const float* __restrict__ masses,
    const float* __restrict__ accum, int N)
{
    int i = blockIdx.x * 256 + threadIdx.x;
    if (i < N) {
        float c = masses[i] / accum[3];
        f[i * 3 + 0] -= c * accum[0];
        f[i * 3 + 1] -= c * accum[1];
        f[i * 3 + 2] -= c * accum[2];
    }
}

extern "C" void kernel_launch(void* const* d_in, const int* in_sizes, int n_in,
                              void* d_out, int out_size, void* d_ws, size_t ws_size,
                              hipStream_t stream)
{
    (void)n_in; (void)ws_size;
    const float* pos    = (const float*)d_in[0];
    const float* masses = (const float*)d_in[1];
    const float* temb   = (const float*)d_in[2];
    const float* Wr1    = (const float*)d_in[3];
    const float* br1    = (const float*)d_in[4];
    const float* Wr2    = (const float*)d_in[5];
    const float* Wself  = (const float*)d_in[6];
    const float* Wo1    = (const float*)d_in[7];
    const float* bo1    = (const float*)d_in[8];
    const float* Wo2    = (const float*)d_in[9];
    const int* types    = (const int*)d_in[10];
    const int* eidx     = (const int*)d_in[11];
    const int N = in_sizes[1];
    const int E = in_sizes[11] / 2;

    float* out = (float*)d_out;
    float* forces = out + 1;

    float* ws = (float*)d_ws;
    float* s_acc = ws;                               // N*32
    float* v_acc = s_acc + (size_t)N * FDIM;         // N*96
    int nAtomBlocks = (N + 7) / 8;
    float* e_partial = v_acc + (size_t)N * 96;       // nAtomBlocks
    float* accum = e_partial + nAtomBlocks;          // 4
    int* counts = (int*)(accum + 4);                 // N
    int* cursor = counts + N;                        // N
    int2* order_sd = (int2*)(cursor + N);            // E int2

    hipMemsetAsync(d_out, 0, (size_t)out_size * sizeof(float), stream);
    hipMemsetAsync(s_acc, 0, (size_t)N * 128 * sizeof(float), stream);
    hipMemsetAsync(counts, 0, (size_t)N * sizeof(int), stream);
    hipMemsetAsync(accum, 0, 4 * sizeof(float), stream);

    hist_dst<<<2048, 256, 0, stream>>>(eidx, counts, E);
    scan_counts<<<1, 1024, 0, stream>>>(counts, cursor, N);
    scatter_edges<<<2048, 256, 0, stream>>>(eidx, cursor, order_sd, E);

    int nEdgeBlocks = (E + CHUNK - 1) / CHUNK;
    edge_fwd_sorted<<<nEdgeBlocks, 256, 0, stream>>>(pos, types, order_sd,
                                                     Wr1, br1, Wr2, temb,
                                                     s_acc, v_acc, E);
    atom_mlp<<<nAtomBlocks, 256, 0, stream>>>(types, temb, Wself, Wo1, bo1, Wo2,
                                              s_acc, v_acc, e_partial, N);
    reduce_energy<<<1, 256, 0, stream>>>(e_partial, nAtomBlocks, out);
    edge_bwd_sorted<<<nEdgeBlocks, 256, 0, stream>>>(pos, types, order_sd,
                                                     Wr1, br1, Wr2, temb,
                                                     s_acc, v_acc, forces, E);
    reduce_net<<<64, 256, 0, stream>>>(forces, masses, accum, N);
    correct_forces<<<(N + 255) / 256, 256, 0, stream>>>(forces, masses, accum, N);
}